// Round 10
// baseline (108.298 us; speedup 1.0000x reference)
//
#include <hip/hip_runtime.h>

// Fused MLPKAN, round 14 — occupancy doubling (TLP), scalar inner kept.
// Evidence: r0 (v2f, 103.0), r12 (scalar, 104.3), r13 (packed, 104.6) are
// indistinguishable => L0 is NOT VALU-issue-bound at REPEAT=1; r11's 73%
// VALUBusy was an instrumentation artifact (reps 2-3 = L1-warm weights).
// Binder: weight-load latency (6 dependent global loads per ii, 1-deep
// prefetch) at only 4 waves/SIMD. Fix: TB 32 -> 16:
//   - LDS 58KB -> 30KB/block, grid 512 -> 1024 = 4 blocks/CU
//   - 32 waves/CU = 8 waves/SIMD (__launch_bounds__(512,8); scalar inner at
//     TB=16 needs ~50 VGPR <= 64, no spill expected)
//   - per-batch arithmetic identical to r12 (absmax 0.0625 expected)
// Predict: kernel ~35 -> ~24-27us, dur_us ~92-97. If >=101: declare
// harness-noise plateau next round.

#define BATCH 16384
#define TB    16

__global__ __launch_bounds__(512, 8) void kan_fused9(
    const float* __restrict__ x,
    const float* __restrict__ A1, const float* __restrict__ a1,
    const float* __restrict__ A2, const float* __restrict__ a2,
    const float* __restrict__ A3, const float* __restrict__ a3,
    const float* __restrict__ B1, const float* __restrict__ c1,
    const float* __restrict__ B2, const float* __restrict__ c2,
    const float* __restrict__ B3, const float* __restrict__ c3,
    float* __restrict__ out)
{
    __shared__ float xs[64][20];        // x transposed: xs[i][b]; rows 80B
    __shared__ float hp[4][TB][64];     // layer0 partials per i-quarter (16KB)
    __shared__ float ht[64][20];        // h transposed: ht[i][b]
    __shared__ float op[4][TB][16];     // layer1 partials per i-quarter

    const int t    = threadIdx.x;
    const int lane = t & 63;
    const int wave = t >> 6;            // 0..7
    const int iq   = wave & 3;          // i-quarter: [16*iq, 16*iq+16)
    const int bh   = wave >> 2;         // batch-half: [8*bh, 8*bh+8)
    const int bB0  = blockIdx.x * TB;

    // ---- stage x transposed: 1024 floats, 512 thr x float2 ----
    {
        const int k = t * 2;
        const float2 v = *(const float2*)(x + (long)bB0 * 64 + k);
        const int b = k >> 6, i = k & 63;
        xs[i][b] = v.x; xs[i + 1][b] = v.y;
    }
    __syncthreads();

    const int boff = 8 * bh;

    // ================= layer 0: 64 -> 64 =================
    {
        const int o  = lane;
        const int i0 = 16 * iq;

        float acc[8];
#pragma unroll
        for (int j = 0; j < 8; ++j) acc[j] = 0.f;
        float bsum = 0.f;

        float2 w1, d1, d2, w3; float4 w2; float b3v;
        {
            const int n = (i0 << 6) + o;
            w1  = *(const float2*)(A1 + 2 * n);
            d1  = *(const float2*)(a1 + 2 * n);
            w2  = *(const float4*)(A2 + 4 * n);
            d2  = *(const float2*)(a2 + 2 * n);
            w3  = *(const float2*)(A3 + 2 * n);
            b3v = a3[n];
        }

#pragma unroll 1
        for (int ii = 0; ii < 16; ++ii) {
            const int i = i0 + ii;
            float2 nw1, nd1, nd2, nw3; float4 nw2; float nb3;
            {
                const int n = ((i0 + ((ii + 1) & 15)) << 6) + o;
                nw1 = *(const float2*)(A1 + 2 * n);
                nd1 = *(const float2*)(a1 + 2 * n);
                nw2 = *(const float4*)(A2 + 4 * n);
                nd2 = *(const float2*)(a2 + 2 * n);
                nw3 = *(const float2*)(A3 + 2 * n);
                nb3 = a3[n];
            }

            const float4 xv0 = *(const float4*)&xs[i][boff];      // ds b128
            const float4 xv1 = *(const float4*)&xs[i][boff + 4];
            const float4 xv[2] = {xv0, xv1};

            bsum += b3v;
#pragma unroll
            for (int j = 0; j < 8; ++j) {
                const float xb = ((const float*)xv)[j];
                float h1a = fmaf(xb, w1.x, d1.x); h1a = fmaxf(h1a, 0.f);
                float h1b = fmaf(xb, w1.y, d1.y); h1b = fmaxf(h1b, 0.f);
                float h2a = fmaf(w2.x, h1a, d2.x); h2a = fmaf(w2.y, h1b, h2a);
                h2a = fmaxf(h2a, 0.f);
                float h2b = fmaf(w2.z, h1a, d2.y); h2b = fmaf(w2.w, h1b, h2b);
                h2b = fmaxf(h2b, 0.f);
                acc[j] = fmaf(w3.x, h2a, fmaf(w3.y, h2b, acc[j]));
            }
            w1 = nw1; d1 = nd1; w2 = nw2; d2 = nd2; w3 = nw3; b3v = nb3;
        }

#pragma unroll
        for (int j = 0; j < 8; ++j)
            hp[iq][boff + j][o] = acc[j] + bsum;   // rows bank-aligned
    }
    __syncthreads();

    // ---- combine i-quarters + transpose: ht[i][b] = sum_q hp[q][b][i] ----
    for (int k = t; k < TB * 64; k += 512) {
        const int b = k >> 6, i = k & 63;
        ht[i][b] = hp[0][b][i] + hp[1][b][i] + hp[2][b][i] + hp[3][b][i];
    }
    __syncthreads();

    // ================= layer 1: 64 -> 16 =================
    {
        const int o1 = lane & 15;
        const int ig = lane >> 4;          // 4 i-subgroups of 4
        const int i0 = 16 * iq + 4 * ig;

        float acc[8];
#pragma unroll
        for (int j = 0; j < 8; ++j) acc[j] = 0.f;
        float bsum = 0.f;

        float2 w1, d1, d2, w3; float4 w2; float b3v;
        {
            const int n = (i0 << 4) + o1;
            w1  = *(const float2*)(B1 + 2 * n);
            d1  = *(const float2*)(c1 + 2 * n);
            w2  = *(const float4*)(B2 + 4 * n);
            d2  = *(const float2*)(c2 + 2 * n);
            w3  = *(const float2*)(B3 + 2 * n);
            b3v = c3[n];
        }

#pragma unroll 1
        for (int ii = 0; ii < 4; ++ii) {
            const int i = i0 + ii;
            float2 nw1, nd1, nd2, nw3; float4 nw2; float nb3;
            {
                const int n = ((i0 + ((ii + 1) & 3)) << 4) + o1;
                nw1 = *(const float2*)(B1 + 2 * n);
                nd1 = *(const float2*)(c1 + 2 * n);
                nw2 = *(const float4*)(B2 + 4 * n);
                nd2 = *(const float2*)(c2 + 2 * n);
                nw3 = *(const float2*)(B3 + 2 * n);
                nb3 = c3[n];
            }

            const float4 hv0 = *(const float4*)&ht[i][boff];
            const float4 hv1 = *(const float4*)&ht[i][boff + 4];
            const float4 hv[2] = {hv0, hv1};

            bsum += b3v;
#pragma unroll
            for (int j = 0; j < 8; ++j) {
                const float hb = ((const float*)hv)[j];
                float h1a = fmaf(hb, w1.x, d1.x); h1a = fmaxf(h1a, 0.f);
                float h1b = fmaf(hb, w1.y, d1.y); h1b = fmaxf(h1b, 0.f);
                float h2a = fmaf(w2.x, h1a, d2.x); h2a = fmaf(w2.y, h1b, h2a);
                h2a = fmaxf(h2a, 0.f);
                float h2b = fmaf(w2.z, h1a, d2.y); h2b = fmaf(w2.w, h1b, h2b);
                h2b = fmaxf(h2b, 0.f);
                acc[j] = fmaf(w3.x, h2a, fmaf(w3.y, h2b, acc[j]));
            }
            w1 = nw1; d1 = nd1; w2 = nw2; d2 = nd2; w3 = nw3; b3v = nb3;
        }

        // reduce over ig (lanes 16 apart), write per-iq partial
#pragma unroll
        for (int j = 0; j < 8; ++j) {
            float v = acc[j] + bsum;
            v += __shfl_xor(v, 16, 64);
            v += __shfl_xor(v, 32, 64);
            if (ig == 0) op[iq][boff + j][o1] = v;
        }
    }
    __syncthreads();

    // ---- store: out = sum_q op[q], 256 floats, float4 coalesced ----
    if (t < 64) {
        const int f = t * 4;
        const float4 p0 = *(const float4*)(&op[0][0][0] + f);
        const float4 p1 = *(const float4*)(&op[1][0][0] + f);
        const float4 p2 = *(const float4*)(&op[2][0][0] + f);
        const float4 p3 = *(const float4*)(&op[3][0][0] + f);
        float4 r;
        r.x = p0.x + p1.x + p2.x + p3.x;
        r.y = p0.y + p1.y + p2.y + p3.y;
        r.z = p0.z + p1.z + p2.z + p3.z;
        r.w = p0.w + p1.w + p2.w + p3.w;
        *(float4*)(out + (long)bB0 * 16 + f) = r;
    }
}

extern "C" void kernel_launch(void* const* d_in, const int* in_sizes, int n_in,
                              void* d_out, int out_size, void* d_ws, size_t ws_size,
                              hipStream_t stream) {
    const float* x     = (const float*)d_in[0];
    const float* l0_W1 = (const float*)d_in[1];
    const float* l0_b1 = (const float*)d_in[2];
    const float* l0_W2 = (const float*)d_in[3];
    const float* l0_b2 = (const float*)d_in[4];
    const float* l0_W3 = (const float*)d_in[5];
    const float* l0_b3 = (const float*)d_in[6];
    const float* l1_W1 = (const float*)d_in[7];
    const float* l1_b1 = (const float*)d_in[8];
    const float* l1_W2 = (const float*)d_in[9];
    const float* l1_b2 = (const float*)d_in[10];
    const float* l1_W3 = (const float*)d_in[11];
    const float* l1_b3 = (const float*)d_in[12];

    float* outp = (float*)d_out;

    dim3 blk(512);
    dim3 grid(BATCH / TB);   // 1024 blocks, 4 per CU, 8 waves/SIMD
    hipLaunchKernelGGL(kan_fused9, grid, blk, 0, stream,
                       x,
                       l0_W1, l0_b1, l0_W2, l0_b2, l0_W3, l0_b3,
                       l1_W1, l1_b1, l1_W2, l1_b2, l1_W3, l1_b3,
                       outp);
}